// Round 1
// baseline (352.847 us; speedup 1.0000x reference)
//
#include <hip/hip_runtime.h>

#define N_NODES 100000
#define N_EDGES 3200000
#define DIN     128
#define DOUT    64

// ---------------------------------------------------------------------------
// Kernel 1: xw = x @ W   ([N,128] @ [128,64] fp32, vector ALU — no fp32 MFMA)
// Block: 256 threads, tile = 64 rows x 64 cols, 4x4 register blocking.
// LDS: Xs 32KB + Ws 32KB = 64KB exactly -> 2 blocks/CU.
// ---------------------------------------------------------------------------
__global__ __launch_bounds__(256) void gemm_xw(const float* __restrict__ x,
                                               const float* __restrict__ w,
                                               float* __restrict__ xw) {
    __shared__ float Xs[64][DIN];   // 64*128*4 = 32 KB (4-way conflict on read, acceptable)
    __shared__ float Ws[DIN][DOUT]; // 128*64*4 = 32 KB

    const int block_row = blockIdx.x * 64;
    const int tid = threadIdx.x;

    // load W (8192 floats, coalesced)
    for (int i = tid; i < DIN * DOUT; i += 256)
        Ws[i >> 6][i & 63] = w[i];

    // load X tile (64 rows x 128, coalesced)
    for (int i = tid; i < 64 * DIN; i += 256) {
        const int r = i >> 7, k = i & 127;
        const int gr = block_row + r;
        Xs[r][k] = (gr < N_NODES) ? x[gr * DIN + k] : 0.f;
    }
    __syncthreads();

    const int tx = tid & 15;   // col group: cols {tx, tx+16, tx+32, tx+48}
    const int ty = tid >> 4;   // row group: rows {ty*4 .. ty*4+3}

    float acc[4][4] = {};
#pragma unroll 4
    for (int k = 0; k < DIN; ++k) {
        float xr[4], wc[4];
#pragma unroll
        for (int j = 0; j < 4; ++j) xr[j] = Xs[ty * 4 + j][k];
#pragma unroll
        for (int i = 0; i < 4; ++i) wc[i] = Ws[k][tx + 16 * i];
#pragma unroll
        for (int j = 0; j < 4; ++j)
#pragma unroll
            for (int i = 0; i < 4; ++i)
                acc[j][i] += xr[j] * wc[i];
    }

#pragma unroll
    for (int j = 0; j < 4; ++j) {
        const int gr = block_row + ty * 4 + j;
        if (gr < N_NODES) {
#pragma unroll
            for (int i = 0; i < 4; ++i)
                xw[gr * DOUT + tx + 16 * i] = acc[j][i];
        }
    }
}

// ---------------------------------------------------------------------------
// Kernel 2: SpMM + GCNII combine, fused.
// One wave (64 lanes) per row; lane = output feature (DOUT == 64).
// Rows are sorted -> per-row edge range via uniform binary search (no atomics).
// out[r] = 0.9 * sum_e vals[e]*xw[cols[e]] + 0.1 * h0[r] + bias
// (theta*s + (1-theta)*s == s, so theta cancels exactly.)
// ---------------------------------------------------------------------------
__global__ __launch_bounds__(256) void spmm_combine(const float* __restrict__ xw,
                                                    const int*   __restrict__ rows,
                                                    const int*   __restrict__ cols,
                                                    const float* __restrict__ vals,
                                                    const float* __restrict__ h0,
                                                    const float* __restrict__ bias,
                                                    float* __restrict__ out) {
    const int wid  = (blockIdx.x * blockDim.x + threadIdx.x) >> 6;
    const int lane = threadIdx.x & 63;
    if (wid >= N_NODES) return;
    const int row = wid;

    // lower_bound(rows, row) ... lower_bound(rows, row+1)  (wave-uniform)
    int lo = 0, hi = N_EDGES;
    while (lo < hi) {
        const int mid = (lo + hi) >> 1;
        if (rows[mid] < row) lo = mid + 1; else hi = mid;
    }
    const int start = lo;
    hi = N_EDGES;
    while (lo < hi) {
        const int mid = (lo + hi) >> 1;
        if (rows[mid] < row + 1) lo = mid + 1; else hi = mid;
    }
    const int end = lo;

    float a0 = 0.f, a1 = 0.f, a2 = 0.f, a3 = 0.f;
    int e = start;
    for (; e + 4 <= end; e += 4) {
        const int   c0 = cols[e],     c1 = cols[e + 1];
        const int   c2 = cols[e + 2], c3 = cols[e + 3];
        const float v0 = vals[e],     v1 = vals[e + 1];
        const float v2 = vals[e + 2], v3 = vals[e + 3];
        a0 += v0 * xw[c0 * DOUT + lane];
        a1 += v1 * xw[c1 * DOUT + lane];
        a2 += v2 * xw[c2 * DOUT + lane];
        a3 += v3 * xw[c3 * DOUT + lane];
    }
    for (; e < end; ++e)
        a0 += vals[e] * xw[cols[e] * DOUT + lane];

    const float hi_sum = (a0 + a1) + (a2 + a3);
    out[row * DOUT + lane] = 0.9f * hi_sum + 0.1f * h0[row * DOUT + lane] + bias[lane];
}

extern "C" void kernel_launch(void* const* d_in, const int* in_sizes, int n_in,
                              void* d_out, int out_size, void* d_ws, size_t ws_size,
                              hipStream_t stream) {
    const float* x    = (const float*)d_in[0];
    const int*   rows = (const int*)  d_in[1];
    const int*   cols = (const int*)  d_in[2];
    const float* vals = (const float*)d_in[3];
    const float* h0   = (const float*)d_in[4];
    const float* w    = (const float*)d_in[5];
    const float* bias = (const float*)d_in[6];
    float* out = (float*)d_out;
    float* xw  = (float*)d_ws;   // N*DOUT fp32 = 25.6 MB scratch

    gemm_xw<<<(N_NODES + 63) / 64, 256, 0, stream>>>(x, w, xw);
    spmm_combine<<<(N_NODES * DOUT + 255) / 256, 256, 0, stream>>>(
        xw, rows, cols, vals, h0, bias, out);
}

// Round 2
// 188.427 us; speedup vs baseline: 1.8726x; 1.8726x over previous
//
#include <hip/hip_runtime.h>

#define N_NODES 100000
#define N_EDGES 3200000
#define DIN     128
#define DOUT    64

// ---------------------------------------------------------------------------
// Kernel 1: xw = x @ W   ([N,128] @ [128,64] fp32, vector ALU — no fp32 MFMA)
// ---------------------------------------------------------------------------
__global__ __launch_bounds__(256) void gemm_xw(const float* __restrict__ x,
                                               const float* __restrict__ w,
                                               float* __restrict__ xw) {
    __shared__ float Xs[64][DIN];   // 32 KB
    __shared__ float Ws[DIN][DOUT]; // 32 KB

    const int block_row = blockIdx.x * 64;
    const int tid = threadIdx.x;

    for (int i = tid; i < DIN * DOUT; i += 256)
        Ws[i >> 6][i & 63] = w[i];

    for (int i = tid; i < 64 * DIN; i += 256) {
        const int r = i >> 7, k = i & 127;
        const int gr = block_row + r;
        Xs[r][k] = (gr < N_NODES) ? x[gr * DIN + k] : 0.f;
    }
    __syncthreads();

    const int tx = tid & 15;
    const int ty = tid >> 4;

    float acc[4][4] = {};
#pragma unroll 4
    for (int k = 0; k < DIN; ++k) {
        float xr[4], wc[4];
#pragma unroll
        for (int j = 0; j < 4; ++j) xr[j] = Xs[ty * 4 + j][k];
#pragma unroll
        for (int i = 0; i < 4; ++i) wc[i] = Ws[k][tx + 16 * i];
#pragma unroll
        for (int j = 0; j < 4; ++j)
#pragma unroll
            for (int i = 0; i < 4; ++i)
                acc[j][i] += xr[j] * wc[i];
    }

#pragma unroll
    for (int j = 0; j < 4; ++j) {
        const int gr = block_row + ty * 4 + j;
        if (gr < N_NODES) {
#pragma unroll
            for (int i = 0; i < 4; ++i)
                xw[gr * DOUT + tx + 16 * i] = acc[j][i];
        }
    }
}

// ---------------------------------------------------------------------------
// Kernel 1b: build row_ptr from the SORTED rows array.
// row_ptr[r] = lower_bound(rows, r). Thread e marks boundaries it owns.
// ---------------------------------------------------------------------------
__global__ __launch_bounds__(256) void build_row_ptr(const int* __restrict__ rows,
                                                     int* __restrict__ row_ptr) {
    const int e = blockIdx.x * blockDim.x + threadIdx.x;
    if (e >= N_EDGES) return;
    const int cur  = rows[e];
    const int prev = (e == 0) ? -1 : rows[e - 1];
    for (int r = prev + 1; r <= cur; ++r) row_ptr[r] = e;
    if (e == N_EDGES - 1) {
        for (int r = cur + 1; r <= N_NODES; ++r) row_ptr[r] = N_EDGES;
    }
}

// ---------------------------------------------------------------------------
// Kernel 2: SpMM + GCNII combine. One wave per row, lane = feature.
// row_ptr gives the edge range in 2 loads (vs 44 dependent binary-search
// loads). 8-deep unroll with 8 accumulators for memory-level parallelism.
// out[r] = 0.9*hi + 0.1*h0[r] + bias   (theta combine is an exact identity)
// ---------------------------------------------------------------------------
__global__ __launch_bounds__(256) void spmm_combine(const float* __restrict__ xw,
                                                    const int*   __restrict__ row_ptr,
                                                    const int*   __restrict__ cols,
                                                    const float* __restrict__ vals,
                                                    const float* __restrict__ h0,
                                                    const float* __restrict__ bias,
                                                    float* __restrict__ out) {
    const int wid  = (blockIdx.x * blockDim.x + threadIdx.x) >> 6;
    const int lane = threadIdx.x & 63;
    if (wid >= N_NODES) return;

    const int row   = __builtin_amdgcn_readfirstlane(wid);
    const int start = __builtin_amdgcn_readfirstlane(row_ptr[row]);
    const int end   = __builtin_amdgcn_readfirstlane(row_ptr[row + 1]);

    float acc[8] = {};
    int e = start;
    for (; e + 8 <= end; e += 8) {
        int   c[8];
        float v[8];
#pragma unroll
        for (int u = 0; u < 8; ++u) { c[u] = cols[e + u]; v[u] = vals[e + u]; }
#pragma unroll
        for (int u = 0; u < 8; ++u)
            acc[u] += v[u] * xw[c[u] * DOUT + lane];
    }
    for (; e < end; ++e)
        acc[0] += vals[e] * xw[cols[e] * DOUT + lane];

    const float s = ((acc[0] + acc[1]) + (acc[2] + acc[3])) +
                    ((acc[4] + acc[5]) + (acc[6] + acc[7]));
    out[row * DOUT + lane] = 0.9f * s + 0.1f * h0[row * DOUT + lane] + bias[lane];
}

// Fallback SpMM with binary search (used only if ws_size can't fit row_ptr).
__global__ __launch_bounds__(256) void spmm_combine_bs(const float* __restrict__ xw,
                                                       const int*   __restrict__ rows,
                                                       const int*   __restrict__ cols,
                                                       const float* __restrict__ vals,
                                                       const float* __restrict__ h0,
                                                       const float* __restrict__ bias,
                                                       float* __restrict__ out) {
    const int wid  = (blockIdx.x * blockDim.x + threadIdx.x) >> 6;
    const int lane = threadIdx.x & 63;
    if (wid >= N_NODES) return;
    const int row = wid;

    int lo = 0, hi = N_EDGES;
    while (lo < hi) { const int mid = (lo + hi) >> 1; if (rows[mid] < row) lo = mid + 1; else hi = mid; }
    const int start = lo;
    hi = N_EDGES;
    while (lo < hi) { const int mid = (lo + hi) >> 1; if (rows[mid] < row + 1) lo = mid + 1; else hi = mid; }
    const int end = lo;

    float acc[8] = {};
    int e = start;
    for (; e + 8 <= end; e += 8) {
#pragma unroll
        for (int u = 0; u < 8; ++u)
            acc[u] += vals[e + u] * xw[cols[e + u] * DOUT + lane];
    }
    for (; e < end; ++e)
        acc[0] += vals[e] * xw[cols[e] * DOUT + lane];

    const float s = ((acc[0] + acc[1]) + (acc[2] + acc[3])) +
                    ((acc[4] + acc[5]) + (acc[6] + acc[7]));
    out[row * DOUT + lane] = 0.9f * s + 0.1f * h0[row * DOUT + lane] + bias[lane];
}

extern "C" void kernel_launch(void* const* d_in, const int* in_sizes, int n_in,
                              void* d_out, int out_size, void* d_ws, size_t ws_size,
                              hipStream_t stream) {
    const float* x    = (const float*)d_in[0];
    const int*   rows = (const int*)  d_in[1];
    const int*   cols = (const int*)  d_in[2];
    const float* vals = (const float*)d_in[3];
    const float* h0   = (const float*)d_in[4];
    const float* w    = (const float*)d_in[5];
    const float* bias = (const float*)d_in[6];
    float* out = (float*)d_out;

    float* xw = (float*)d_ws;                       // N*DOUT fp32 = 25.6 MB
    const size_t xw_bytes = (size_t)N_NODES * DOUT * sizeof(float);
    int* row_ptr = (int*)((char*)d_ws + xw_bytes);  // (N+1) ints = 400 KB

    gemm_xw<<<(N_NODES + 63) / 64, 256, 0, stream>>>(x, w, xw);

    if (ws_size >= xw_bytes + (size_t)(N_NODES + 1) * sizeof(int)) {
        build_row_ptr<<<(N_EDGES + 255) / 256, 256, 0, stream>>>(rows, row_ptr);
        spmm_combine<<<(N_NODES * DOUT + 255) / 256, 256, 0, stream>>>(
            xw, row_ptr, cols, vals, h0, bias, out);
    } else {
        spmm_combine_bs<<<(N_NODES * DOUT + 255) / 256, 256, 0, stream>>>(
            xw, rows, cols, vals, h0, bias, out);
    }
}

// Round 3
// 112.671 us; speedup vs baseline: 3.1317x; 1.6724x over previous
//
#include <hip/hip_runtime.h>

#define N_NODES 100000
#define N_EDGES 3200000
#define DIN     128
#define DOUT    64

typedef unsigned short bf16_t;

__device__ __forceinline__ float bf16_to_f32(bf16_t h) {
    union { unsigned int u; float f; } un;
    un.u = ((unsigned int)h) << 16;
    return un.f;
}
__device__ __forceinline__ bf16_t f32_to_bf16(float f) {
    union { float f; unsigned int u; } un; un.f = f;
    unsigned int u = un.u + 0x7fffu + ((un.u >> 16) & 1u);  // round-nearest-even
    return (bf16_t)(u >> 16);
}

// ---------------------------------------------------------------------------
// Kernel 1: xw_bf16 = bf16(x @ W).  64-row x 64-col tile, 4x4 reg blocking,
// all-float4 LDS reads. Xs is XOR-swizzled along k (2-way conflicts = free).
// ---------------------------------------------------------------------------
__global__ __launch_bounds__(256) void gemm_xw_bf16(const float* __restrict__ x,
                                                    const float* __restrict__ w,
                                                    bf16_t* __restrict__ xwb) {
    __shared__ float Xs[64][DIN];   // element (r,k) lives at float4-index (k/4) ^ (r&7)
    __shared__ float Ws[DIN][DOUT]; // linear

    const int tid = threadIdx.x;
    const int block_row = blockIdx.x * 64;

    // stage W (8192 floats) as float4, linear
    {
        const float4* w4 = (const float4*)w;
        float4* ws4 = (float4*)Ws;
        for (int i = tid; i < DIN * DOUT / 4; i += 256)
            ws4[i] = w4[i];
    }
    // stage X tile (64 x 128) as float4, swizzled
    for (int i = tid; i < 64 * DIN / 4; i += 256) {
        const int r  = i >> 5;        // 32 float4 per row
        const int k4 = i & 31;
        const int gr = block_row + r;
        float4 v = make_float4(0.f, 0.f, 0.f, 0.f);
        if (gr < N_NODES) v = ((const float4*)x)[gr * (DIN / 4) + k4];
        ((float4*)&Xs[r][0])[k4 ^ (r & 7)] = v;
    }
    __syncthreads();

    const int tx = tid & 15;   // cols tx*4 .. tx*4+3
    const int ty = tid >> 4;   // rows ty*4 .. ty*4+3

    float acc[4][4] = {};
#pragma unroll 2
    for (int k4 = 0; k4 < DIN / 4; ++k4) {
        float4 xr[4];
#pragma unroll
        for (int j = 0; j < 4; ++j) {
            const int r = ty * 4 + j;
            xr[j] = ((const float4*)&Xs[r][0])[k4 ^ (r & 7)];
        }
#pragma unroll
        for (int kk = 0; kk < 4; ++kk) {
            const float4 wv = ((const float4*)Ws)[(k4 * 4 + kk) * (DOUT / 4) + tx];
            const float xv0 = (kk == 0) ? xr[0].x : (kk == 1) ? xr[0].y : (kk == 2) ? xr[0].z : xr[0].w;
            const float xv1 = (kk == 0) ? xr[1].x : (kk == 1) ? xr[1].y : (kk == 2) ? xr[1].z : xr[1].w;
            const float xv2 = (kk == 0) ? xr[2].x : (kk == 1) ? xr[2].y : (kk == 2) ? xr[2].z : xr[2].w;
            const float xv3 = (kk == 0) ? xr[3].x : (kk == 1) ? xr[3].y : (kk == 2) ? xr[3].z : xr[3].w;
            acc[0][0] += xv0 * wv.x; acc[0][1] += xv0 * wv.y; acc[0][2] += xv0 * wv.z; acc[0][3] += xv0 * wv.w;
            acc[1][0] += xv1 * wv.x; acc[1][1] += xv1 * wv.y; acc[1][2] += xv1 * wv.z; acc[1][3] += xv1 * wv.w;
            acc[2][0] += xv2 * wv.x; acc[2][1] += xv2 * wv.y; acc[2][2] += xv2 * wv.z; acc[2][3] += xv2 * wv.w;
            acc[3][0] += xv3 * wv.x; acc[3][1] += xv3 * wv.y; acc[3][2] += xv3 * wv.z; acc[3][3] += xv3 * wv.w;
        }
    }

#pragma unroll
    for (int j = 0; j < 4; ++j) {
        const int gr = block_row + ty * 4 + j;
        if (gr < N_NODES) {
            const unsigned int p0 = (unsigned int)f32_to_bf16(acc[j][0]) |
                                    ((unsigned int)f32_to_bf16(acc[j][1]) << 16);
            const unsigned int p1 = (unsigned int)f32_to_bf16(acc[j][2]) |
                                    ((unsigned int)f32_to_bf16(acc[j][3]) << 16);
            uint2 pk; pk.x = p0; pk.y = p1;
            *(uint2*)&xwb[gr * DOUT + tx * 4] = pk;
        }
    }
}

// ---------------------------------------------------------------------------
// Kernel 1b: row_ptr[r] = lower_bound(rows, r) from the SORTED rows array.
// ---------------------------------------------------------------------------
__global__ __launch_bounds__(256) void build_row_ptr(const int* __restrict__ rows,
                                                     int* __restrict__ row_ptr) {
    const int e = blockIdx.x * blockDim.x + threadIdx.x;
    if (e >= N_EDGES) return;
    const int cur  = rows[e];
    const int prev = (e == 0) ? -1 : rows[e - 1];
    for (int r = prev + 1; r <= cur; ++r) row_ptr[r] = e;
    if (e == N_EDGES - 1) {
        for (int r = cur + 1; r <= N_NODES; ++r) row_ptr[r] = N_EDGES;
    }
}

// ---------------------------------------------------------------------------
// Kernel 2: SpMM + combine. One wave per row, lane = feature. bf16 gathers
// (128 B/row), 16-deep unroll for MLP, nontemporal h0/out streaming so the
// 51 MB of streams don't evict xw from L2.
// ---------------------------------------------------------------------------
__global__ __launch_bounds__(256) void spmm_combine(const bf16_t* __restrict__ xwb,
                                                    const int*    __restrict__ row_ptr,
                                                    const int*    __restrict__ cols,
                                                    const float*  __restrict__ vals,
                                                    const float*  __restrict__ h0,
                                                    const float*  __restrict__ bias,
                                                    float* __restrict__ out) {
    const int wid  = (blockIdx.x * blockDim.x + threadIdx.x) >> 6;
    const int lane = threadIdx.x & 63;
    if (wid >= N_NODES) return;

    const int row   = __builtin_amdgcn_readfirstlane(wid);
    const int start = __builtin_amdgcn_readfirstlane(row_ptr[row]);
    const int end   = __builtin_amdgcn_readfirstlane(row_ptr[row + 1]);

    float acc[16] = {};
    int e = start;
    for (; e + 16 <= end; e += 16) {
        int   c[16];
        float v[16];
#pragma unroll
        for (int u = 0; u < 16; ++u) { c[u] = cols[e + u]; v[u] = vals[e + u]; }
#pragma unroll
        for (int u = 0; u < 16; ++u)
            acc[u] += v[u] * bf16_to_f32(xwb[c[u] * DOUT + lane]);
    }
    for (; e + 4 <= end; e += 4) {
        int   c[4];
        float v[4];
#pragma unroll
        for (int u = 0; u < 4; ++u) { c[u] = cols[e + u]; v[u] = vals[e + u]; }
#pragma unroll
        for (int u = 0; u < 4; ++u)
            acc[u] += v[u] * bf16_to_f32(xwb[c[u] * DOUT + lane]);
    }
    for (; e < end; ++e)
        acc[0] += vals[e] * bf16_to_f32(xwb[cols[e] * DOUT + lane]);

    float s = 0.f;
#pragma unroll
    for (int u = 0; u < 8; ++u) s += (acc[u] + acc[u + 8]);

    const float h = __builtin_nontemporal_load(&h0[row * DOUT + lane]);
    const float r = 0.9f * s + 0.1f * h + bias[lane];
    __builtin_nontemporal_store(r, &out[row * DOUT + lane]);
}

// Fallback (only if ws_size is too small for row_ptr): binary search variant.
__global__ __launch_bounds__(256) void spmm_combine_bs(const bf16_t* __restrict__ xwb,
                                                       const int*    __restrict__ rows,
                                                       const int*    __restrict__ cols,
                                                       const float*  __restrict__ vals,
                                                       const float*  __restrict__ h0,
                                                       const float*  __restrict__ bias,
                                                       float* __restrict__ out) {
    const int wid  = (blockIdx.x * blockDim.x + threadIdx.x) >> 6;
    const int lane = threadIdx.x & 63;
    if (wid >= N_NODES) return;
    const int row = wid;

    int lo = 0, hi = N_EDGES;
    while (lo < hi) { const int mid = (lo + hi) >> 1; if (rows[mid] < row) lo = mid + 1; else hi = mid; }
    const int start = lo;
    hi = N_EDGES;
    while (lo < hi) { const int mid = (lo + hi) >> 1; if (rows[mid] < row + 1) lo = mid + 1; else hi = mid; }
    const int end = lo;

    float acc[8] = {};
    int e = start;
    for (; e + 8 <= end; e += 8) {
#pragma unroll
        for (int u = 0; u < 8; ++u)
            acc[u] += vals[e + u] * bf16_to_f32(xwb[cols[e + u] * DOUT + lane]);
    }
    for (; e < end; ++e)
        acc[0] += vals[e] * bf16_to_f32(xwb[cols[e] * DOUT + lane]);

    const float s = ((acc[0] + acc[1]) + (acc[2] + acc[3])) +
                    ((acc[4] + acc[5]) + (acc[6] + acc[7]));
    out[row * DOUT + lane] = 0.9f * s + 0.1f * h0[row * DOUT + lane] + bias[lane];
}

extern "C" void kernel_launch(void* const* d_in, const int* in_sizes, int n_in,
                              void* d_out, int out_size, void* d_ws, size_t ws_size,
                              hipStream_t stream) {
    const float* x    = (const float*)d_in[0];
    const int*   rows = (const int*)  d_in[1];
    const int*   cols = (const int*)  d_in[2];
    const float* vals = (const float*)d_in[3];
    const float* h0   = (const float*)d_in[4];
    const float* w    = (const float*)d_in[5];
    const float* bias = (const float*)d_in[6];
    float* out = (float*)d_out;

    bf16_t* xwb = (bf16_t*)d_ws;                         // N*DOUT bf16 = 12.8 MB
    const size_t xw_bytes = (size_t)N_NODES * DOUT * sizeof(bf16_t);
    int* row_ptr = (int*)((char*)d_ws + xw_bytes);       // (N+1) ints = 400 KB

    gemm_xw_bf16<<<(N_NODES + 63) / 64, 256, 0, stream>>>(x, w, xwb);

    if (ws_size >= xw_bytes + (size_t)(N_NODES + 1) * sizeof(int)) {
        build_row_ptr<<<(N_EDGES + 255) / 256, 256, 0, stream>>>(rows, row_ptr);
        spmm_combine<<<(N_NODES * DOUT + 255) / 256, 256, 0, stream>>>(
            xwb, row_ptr, cols, vals, h0, bias, out);
    } else {
        spmm_combine_bs<<<(N_NODES * DOUT + 255) / 256, 256, 0, stream>>>(
            xwb, rows, cols, vals, h0, bias, out);
    }
}